// Round 3
// baseline (3654.806 us; speedup 1.0000x reference)
//
#include <hip/hip_runtime.h>
#include <hip/hip_bf16.h>
#include <stdint.h>

#define B_     2
#define S_     2048
#define H_     2048
#define NH_    16
#define QLORA  1536
#define KVLORA 512
#define DNOPE  128
#define DROPE  64
#define DV     128
#define DQK    192
#define INTER_ 8192
#define NTOK   4096   // B_*S_
#define CKV_LD 640    // kv_a output padded 576 -> 640 cols

typedef unsigned short u16;
typedef __attribute__((ext_vector_type(8))) short bf16x8;   // 8 bf16 (4 VGPRs)
typedef __attribute__((ext_vector_type(4))) float f32x4;    // MFMA C/D

// ---------------- bf16 split helpers (x = hi + lo, each bf16) ---------------
__device__ __forceinline__ u16 f2bf(float x) {
    union { __hip_bfloat16 b; u16 u; } cv; cv.b = __float2bfloat16(x); return cv.u;
}
__device__ __forceinline__ float bf2f(u16 u) {
    union { __hip_bfloat16 b; u16 u; } cv; cv.u = u; return __bfloat162float(cv.b);
}
__device__ __forceinline__ void split2(float x, u16& h, u16& l) {
    h = f2bf(x);
    l = f2bf(x - bf2f(h));
}

// async global->LDS, 16B per lane (LDS dest = wave-uniform base + lane*16)
__device__ __forceinline__ void async_ld16(const void* g, void* l) {
    __builtin_amdgcn_global_load_lds(
        (const __attribute__((address_space(1))) char*)g,
        (__attribute__((address_space(3))) char*)l, 16, 0, 0);
}

// ---------------------------------------------------------------------------
// split: fp32 -> (hi,lo) bf16.  i >= nvalid reads as 0 (zero-padding).
// ---------------------------------------------------------------------------
__global__ __launch_bounds__(256)
void split_kernel(const float* __restrict__ in, u16* __restrict__ hi,
                  u16* __restrict__ lo, int n, int nvalid)
{
    int i0 = (blockIdx.x * 256 + threadIdx.x) * 4;
    int stride = gridDim.x * 1024;
    for (int i = i0; i < n; i += stride) {
        float4 v = make_float4(0.f, 0.f, 0.f, 0.f);
        if (i < nvalid) v = *(const float4*)(in + i);
        ushort4 h, l;
        split2(v.x, h.x, l.x);
        split2(v.y, h.y, l.y);
        split2(v.z, h.z, l.z);
        split2(v.w, h.w, l.w);
        *(ushort4*)(hi + i) = h;
        *(ushort4*)(lo + i) = l;
    }
}

// strided variant: rows x cols slice out of a [rows][ld] fp32 matrix
__global__ __launch_bounds__(256)
void split_strided_kernel(const float* __restrict__ in, u16* __restrict__ hi,
                          u16* __restrict__ lo, int cols, int ld)
{
    int r = blockIdx.y;
    int c = (blockIdx.x * 256 + threadIdx.x) * 4;
    if (c >= cols) return;
    float4 v = *(const float4*)(in + (size_t)r * ld + c);
    ushort4 h, l;
    split2(v.x, h.x, l.x);
    split2(v.y, h.y, l.y);
    split2(v.z, h.z, l.z);
    split2(v.w, h.w, l.w);
    *(ushort4*)(hi + (size_t)r * cols + c) = h;
    *(ushort4*)(lo + (size_t)r * cols + c) = l;
}

// ---------------------------------------------------------------------------
// RMSNorm -> (hi,lo) bf16 outputs (packed [rows][cols]).
// ---------------------------------------------------------------------------
__global__ __launch_bounds__(256)
void rmsnorm_split_kernel(const float* __restrict__ in, const float* __restrict__ w,
                          u16* __restrict__ hi, u16* __restrict__ lo,
                          int cols, int in_stride)
{
    int row = blockIdx.x;
    const float* x = in + (size_t)row * in_stride;
    int tid = threadIdx.x;

    float ss = 0.f;
    for (int c = tid * 4; c < cols; c += 1024) {
        float4 v = *(const float4*)(x + c);
        ss += v.x*v.x + v.y*v.y + v.z*v.z + v.w*v.w;
    }
    for (int off = 32; off > 0; off >>= 1) ss += __shfl_down(ss, off, 64);
    __shared__ float red[4];
    int wave = tid >> 6, lane = tid & 63;
    if (lane == 0) red[wave] = ss;
    __syncthreads();
    if (tid == 0) red[0] = red[0] + red[1] + red[2] + red[3];
    __syncthreads();
    float r = 1.0f / sqrtf(red[0] / (float)cols + 1e-6f);

    for (int c = tid * 4; c < cols; c += 1024) {
        float4 v = *(const float4*)(x + c);
        float4 wv = *(const float4*)(w + c);
        float o0 = wv.x * (v.x * r), o1 = wv.y * (v.y * r);
        float o2 = wv.z * (v.z * r), o3 = wv.w * (v.w * r);
        ushort4 h, l;
        split2(o0, h.x, l.x); split2(o1, h.y, l.y);
        split2(o2, h.z, l.z); split2(o3, h.w, l.w);
        *(ushort4*)(hi + (size_t)row * cols + c) = h;
        *(ushort4*)(lo + (size_t)row * cols + c) = l;
    }
}

// ---------------------------------------------------------------------------
// RoPE: in-place on q's pe slice; ckv[:,512:576] -> kpe_out. (fp32)
// ---------------------------------------------------------------------------
__global__ __launch_bounds__(256)
void rope_kernel(float* __restrict__ q, const float* __restrict__ ckv,
                 float* __restrict__ kpe_out, const int* __restrict__ pos_ids)
{
    int gid = blockIdx.x * 8 + (threadIdx.x >> 5);
    int j   = threadIdx.x & 31;
    int tok = gid / 17;
    int unit = gid - tok * 17;
    bool valid = tok < NTOK;    // grid sized exactly; always true

    float x0 = 0.f, x1 = 0.f, c = 0.f, sn = 0.f;
    const float* src = nullptr;
    float* dst = nullptr;
    if (valid) {
        float pos  = (float)pos_ids[tok];
        float freq = powf(10000.0f, -(float)j / 32.0f);
        float ang  = pos * freq;
        c = cosf(ang); sn = sinf(ang);
        if (unit < NH_) {
            float* base = q + (size_t)tok * (NH_ * DQK) + unit * DQK + DNOPE;
            src = base; dst = base;
        } else {
            src = ckv + (size_t)tok * CKV_LD + KVLORA;
            dst = kpe_out + (size_t)tok * DROPE;
        }
        x0 = src[2 * j];
        x1 = src[2 * j + 1];
    }
    __syncthreads();   // all loads complete before in-place stores
    if (valid) {
        dst[j]      = x0 * c - x1 * sn;
        dst[j + 32] = x1 * c + x0 * sn;
    }
}

// ---------------------------------------------------------------------------
// bf16x3 MFMA GEMM:  C[M,N] = A[M,K] @ B[N,K]^T with A=Ah+Al, B=Bh+Bl.
// acc += Ah*Bh + Ah*Bl + Al*Bh  (fp32 accum; error ~2^-17)
// 128x128 tile, BK=32, 256 thr = 4 waves (2x2), 64x64 per wave, 4x4 frags.
// EPI: 0 C=v | 1 C+=v | 2 C=auxf+v | 3 (Oh,Ol)=split(silu(v)) |
//      4 (Oh,Ol)=split((SHi+SLo)*v)   [S and O may ALIAS -> no restrict]
// M%128==0, N%128==0, K%32==0.
// ---------------------------------------------------------------------------
template<int EPI>
__global__ __launch_bounds__(256)
void gemm_bf16x3(const u16* __restrict__ Ahi, const u16* __restrict__ Alo,
                 const u16* __restrict__ Bhi, const u16* __restrict__ Blo,
                 float* __restrict__ C, const float* __restrict__ auxf,
                 const u16* SHi, const u16* SLo,
                 u16* OHi, u16* OLo,
                 int M, int N, int K)
{
    __shared__ u16 sAh[128 * 32];
    __shared__ u16 sAl[128 * 32];
    __shared__ u16 sBh[128 * 32];
    __shared__ u16 sBl[128 * 32];

    const int tid = threadIdx.x;
    const int m0 = blockIdx.y * 128, n0 = blockIdx.x * 128;
    const int lane = tid & 63, wid = tid >> 6;
    const int wr = wid >> 1, wc = wid & 1;        // wave tile (64x64)
    const int lr = lane & 15, kg = lane >> 4;     // frag row/col, k-group

    f32x4 acc[4][4];
#pragma unroll
    for (int m = 0; m < 4; ++m)
#pragma unroll
        for (int n = 0; n < 4; ++n) { f32x4 z = {0.f,0.f,0.f,0.f}; acc[m][n] = z; }

    // staging: thread t covers 8 bf16 at row u*64 + (t>>2), col (t&3)*8
    const int srow = tid >> 2, scol = (tid & 3) * 8;
    const u16* gA0 = Ahi + (size_t)(m0 + srow) * K + scol;
    const u16* gA1 = Alo + (size_t)(m0 + srow) * K + scol;
    const u16* gB0 = Bhi + (size_t)(n0 + srow) * K + scol;
    const u16* gB1 = Blo + (size_t)(n0 + srow) * K + scol;
    const size_t rstep = (size_t)64 * K;

    for (int k0 = 0; k0 < K; k0 += 32) {
        __syncthreads();
#pragma unroll
        for (int u = 0; u < 2; ++u) {
            int lo_ = (u * 256 + tid) * 8;
            async_ld16(gA0 + u * rstep + k0, sAh + lo_);
            async_ld16(gA1 + u * rstep + k0, sAl + lo_);
            async_ld16(gB0 + u * rstep + k0, sBh + lo_);
            async_ld16(gB1 + u * rstep + k0, sBl + lo_);
        }
        __syncthreads();   // drains vmcnt before s_barrier

        bf16x8 ah[4], al[4], bh[4], bl[4];
#pragma unroll
        for (int m = 0; m < 4; ++m) {
            int off = (wr * 64 + m * 16 + lr) * 32 + kg * 8;
            ah[m] = *(const bf16x8*)(sAh + off);
            al[m] = *(const bf16x8*)(sAl + off);
        }
#pragma unroll
        for (int n = 0; n < 4; ++n) {
            int off = (wc * 64 + n * 16 + lr) * 32 + kg * 8;
            bh[n] = *(const bf16x8*)(sBh + off);
            bl[n] = *(const bf16x8*)(sBl + off);
        }
#pragma unroll
        for (int m = 0; m < 4; ++m)
#pragma unroll
            for (int n = 0; n < 4; ++n) {
                acc[m][n] = __builtin_amdgcn_mfma_f32_16x16x32_bf16(ah[m], bh[n], acc[m][n], 0, 0, 0);
                acc[m][n] = __builtin_amdgcn_mfma_f32_16x16x32_bf16(ah[m], bl[n], acc[m][n], 0, 0, 0);
                acc[m][n] = __builtin_amdgcn_mfma_f32_16x16x32_bf16(al[m], bh[n], acc[m][n], 0, 0, 0);
            }
    }

    // C/D layout: col = lane&15, row = (lane>>4)*4 + j   [guide §3, m89-verified]
    const int row0 = m0 + wr * 64 + kg * 4;
    const int col0 = n0 + wc * 64 + lr;
#pragma unroll
    for (int m = 0; m < 4; ++m)
#pragma unroll
        for (int n = 0; n < 4; ++n)
#pragma unroll
            for (int j = 0; j < 4; ++j) {
                int r = row0 + m * 16 + j;
                int c = col0 + n * 16;
                size_t idx = (size_t)r * N + c;
                float v = acc[m][n][j];
                if (EPI == 0) C[idx] = v;
                else if (EPI == 1) C[idx] += v;
                else if (EPI == 2) C[idx] = auxf[idx] + v;
                else if (EPI == 3) {
                    float s = v / (1.f + expf(-v));
                    u16 h, l; split2(s, h, l);
                    OHi[idx] = h; OLo[idx] = l;
                } else {
                    float s = bf2f(SHi[idx]) + bf2f(SLo[idx]);
                    float hv = s * v;
                    u16 h, l; split2(hv, h, l);
                    OHi[idx] = h; OLo[idx] = l;
                }
            }
}

// ---------------------------------------------------------------------------
// Flash-style causal MLA attention, fp32 vector. Output -> (hi,lo) bf16 split.
// ---------------------------------------------------------------------------
__global__ __launch_bounds__(256)
void attn_kernel(const float* __restrict__ q,     // [NTOK, 3072]
                 const float* __restrict__ kvup,  // [NTOK, 4096]
                 const float* __restrict__ kpe,   // [NTOK, 64]
                 u16* __restrict__ ahi,           // [NTOK, 2048]
                 u16* __restrict__ alo)
{
    int blk = blockIdx.x;
    int qt = 31 - (blk & 31);          // heavy tiles dispatch first
    int bh = blk >> 5;
    int h = bh & 15, b = bh >> 4;
    int qtok0 = b * S_ + qt * 64;

    __shared__ __align__(16) float Qs[32][68];
    __shared__ __align__(16) float Ks[32][68];
    __shared__ __align__(16) float Ps[64][68];
    __shared__ __align__(16) float Vs[32][132];

    int tid = threadIdx.x;
    int tx = tid & 15, ty = tid >> 4;

    float m_run[4], l_run[4], Oc[4][8];
#pragma unroll
    for (int i = 0; i < 4; ++i) {
        m_run[i] = -1e30f; l_run[i] = 0.f;
#pragma unroll
        for (int jj = 0; jj < 8; ++jj) Oc[i][jj] = 0.f;
    }
    const float scale = 0.07216878364870323f;  // 192^-0.5

    for (int kt = 0; kt <= qt; ++kt) {
        int ktok0 = b * S_ + kt * 64;

        float sacc[4][4];
#pragma unroll
        for (int i = 0; i < 4; ++i)
#pragma unroll
            for (int jj = 0; jj < 4; ++jj) sacc[i][jj] = 0.f;

        for (int dc = 0; dc < 6; ++dc) {
            __syncthreads();
#pragma unroll
            for (int u = 0; u < 2; ++u) {
                int f = tid + u * 256;
                int r = f >> 3;
                int kq = (f & 7) * 4;
                int d = dc * 32 + kq;
                float4 qv = *(const float4*)(q + (size_t)(qtok0 + r) * 3072 + h * DQK + d);
                Qs[kq + 0][r] = qv.x; Qs[kq + 1][r] = qv.y;
                Qs[kq + 2][r] = qv.z; Qs[kq + 3][r] = qv.w;
                float4 kv;
                if (dc < 4) kv = *(const float4*)(kvup + (size_t)(ktok0 + r) * 4096 + h * 256 + d);
                else        kv = *(const float4*)(kpe  + (size_t)(ktok0 + r) * 64 + (d - 128));
                Ks[kq + 0][r] = kv.x; Ks[kq + 1][r] = kv.y;
                Ks[kq + 2][r] = kv.z; Ks[kq + 3][r] = kv.w;
            }
            __syncthreads();
#pragma unroll
            for (int kk = 0; kk < 32; ++kk) {
                float4 qa = *(const float4*)&Qs[kk][ty * 4];
                float4 kb = *(const float4*)&Ks[kk][tx * 4];
                float qv[4] = {qa.x, qa.y, qa.z, qa.w};
                float kv[4] = {kb.x, kb.y, kb.z, kb.w};
#pragma unroll
                for (int i = 0; i < 4; ++i)
#pragma unroll
                    for (int jj = 0; jj < 4; ++jj) sacc[i][jj] += qv[i] * kv[jj];
            }
        }

        float p[4][4];
#pragma unroll
        for (int i = 0; i < 4; ++i) {
            int qg = qt * 64 + ty * 4 + i;
            float rm = -1e30f;
#pragma unroll
            for (int jj = 0; jj < 4; ++jj) {
                int kg = kt * 64 + tx * 4 + jj;
                float sv = sacc[i][jj] * scale;
                if (kg > qg) sv = -1e30f;
                sacc[i][jj] = sv;
                rm = fmaxf(rm, sv);
            }
            for (int off = 1; off < 16; off <<= 1) rm = fmaxf(rm, __shfl_xor(rm, off, 16));
            float mnew = fmaxf(m_run[i], rm);
            float rs = 0.f;
#pragma unroll
            for (int jj = 0; jj < 4; ++jj) {
                float pv = expf(sacc[i][jj] - mnew);
                p[i][jj] = pv; rs += pv;
            }
            for (int off = 1; off < 16; off <<= 1) rs += __shfl_xor(rs, off, 16);
            float corr = expf(m_run[i] - mnew);
            l_run[i] = l_run[i] * corr + rs;
            m_run[i] = mnew;
#pragma unroll
            for (int jj = 0; jj < 8; ++jj) Oc[i][jj] *= corr;
        }
#pragma unroll
        for (int i = 0; i < 4; ++i)
            *(float4*)&Ps[ty * 4 + i][tx * 4] = make_float4(p[i][0], p[i][1], p[i][2], p[i][3]);

        for (int vc = 0; vc < 2; ++vc) {
            __syncthreads();
#pragma unroll
            for (int u = 0; u < 4; ++u) {
                int f = tid + u * 256;
                int r = f >> 5;
                int cq = (f & 31) * 4;
                float4 vv = *(const float4*)(kvup + (size_t)(ktok0 + vc * 32 + r) * 4096 + h * 256 + 128 + cq);
                *(float4*)&Vs[r][cq] = vv;
            }
            __syncthreads();
#pragma unroll 4
            for (int kk2 = 0; kk2 < 32; ++kk2) {
                int kk = vc * 32 + kk2;
                float4 v0 = *(const float4*)&Vs[kk2][tx * 8];
                float4 v1 = *(const float4*)&Vs[kk2][tx * 8 + 4];
#pragma unroll
                for (int i = 0; i < 4; ++i) {
                    float pv = Ps[ty * 4 + i][kk];
                    Oc[i][0] += pv * v0.x; Oc[i][1] += pv * v0.y;
                    Oc[i][2] += pv * v0.z; Oc[i][3] += pv * v0.w;
                    Oc[i][4] += pv * v1.x; Oc[i][5] += pv * v1.y;
                    Oc[i][6] += pv * v1.z; Oc[i][7] += pv * v1.w;
                }
            }
        }
    }

#pragma unroll
    for (int i = 0; i < 4; ++i) {
        int tok = qtok0 + ty * 4 + i;
        float inv = 1.0f / l_run[i];
        ushort4 h0, h1, l0, l1;
        split2(Oc[i][0] * inv, h0.x, l0.x); split2(Oc[i][1] * inv, h0.y, l0.y);
        split2(Oc[i][2] * inv, h0.z, l0.z); split2(Oc[i][3] * inv, h0.w, l0.w);
        split2(Oc[i][4] * inv, h1.x, l1.x); split2(Oc[i][5] * inv, h1.y, l1.y);
        split2(Oc[i][6] * inv, h1.z, l1.z); split2(Oc[i][7] * inv, h1.w, l1.w);
        size_t o = (size_t)tok * 2048 + h * 128 + tx * 8;
        *(ushort4*)(ahi + o) = h0; *(ushort4*)(ahi + o + 4) = h1;
        *(ushort4*)(alo + o) = l0; *(ushort4*)(alo + o + 4) = l1;
    }
}

// ---------------------------------------------------------------------------
// Workspace layout (peak 234 MB; lifetime-packed):
//  [  0, 17) w_hi   weight split scratch (reused by every GEMM)
//  [ 17, 34) w_lo
//  [ 34, 51) xn_hi -> qa_hi (step4+) -> x2n_hi (step11+)
//  [ 51, 68) xn_lo -> qa_lo          -> x2n_lo
//  [ 68,102) kvup (fp32, steps 7-9) -> s/h_hi (steps 12-14)
//  [102,136)                         -> s/h_lo
//  [136,187) q_f32 (steps 5-9)
//  [187,213) qa_f32 (steps 2-4) -> attn_hi[187,204)+attn_lo[204,221) (9-10)
//  [221,232) ckv_f32 (steps 3-8)
//  [232,234) kpe (steps 8-9)
// ---------------------------------------------------------------------------
extern "C" void kernel_launch(void* const* d_in, const int* in_sizes, int n_in,
                              void* d_out, int out_size, void* d_ws, size_t ws_size,
                              hipStream_t stream)
{
    const float* hidden    = (const float*)d_in[0];
    const int*   pos_ids   = (const int*)  d_in[1];
    const float* in_ln_w   = (const float*)d_in[2];
    const float* post_ln_w = (const float*)d_in[3];
    const float* q_a_w     = (const float*)d_in[4];
    const float* q_a_ln_w  = (const float*)d_in[5];
    const float* q_b_w     = (const float*)d_in[6];
    const float* kv_a_w    = (const float*)d_in[7];
    const float* kv_a_ln_w = (const float*)d_in[8];
    const float* kv_b_w    = (const float*)d_in[9];
    const float* o_w       = (const float*)d_in[10];
    const float* gate_w    = (const float*)d_in[11];
    const float* up_w      = (const float*)d_in[12];
    const float* down_w    = (const float*)d_in[13];
    float* out = (float*)d_out;
    char* base = (char*)d_ws;
    const size_t MB = 1ull << 20;

    u16*   w_hi    = (u16*)  (base +   0 * MB);
    u16*   w_lo    = (u16*)  (base +  17 * MB);
    u16*   xn_hi   = (u16*)  (base +  34 * MB);   // also qa_hi / x2n_hi
    u16*   xn_lo   = (u16*)  (base +  51 * MB);   // also qa_lo / x2n_lo
    float* kvup    = (float*)(base +  68 * MB);
    u16*   sh_hi   = (u16*)  (base +  68 * MB);   // over kvup (dead)
    u16*   sh_lo   = (u16*)  (base + 102 * MB);
    float* q_f32   = (float*)(base + 136 * MB);
    float* qa_f32  = (float*)(base + 187 * MB);
    u16*   attn_hi = (u16*)  (base + 187 * MB);   // over qa_f32 (dead)
    u16*   attn_lo = (u16*)  (base + 204 * MB);
    float* ckv_f32 = (float*)(base + 221 * MB);
    float* kpe     = (float*)(base + 232 * MB);

    dim3 blk(256);
    auto splitw = [&](const float* in, int n, int nvalid) {
        int blocks = (n / 4 + 255) / 256; if (blocks > 2048) blocks = 2048;
        split_kernel<<<blocks, blk, 0, stream>>>(in, w_hi, w_lo, n, nvalid);
    };
#define GEMM(EPI, Ah, Al, Cp, Aux, Sh, Sl, Oh, Ol, Mv, Nv, Kv) \
    gemm_bf16x3<EPI><<<dim3((Nv)/128, (Mv)/128), blk, 0, stream>>>( \
        Ah, Al, w_hi, w_lo, Cp, Aux, Sh, Sl, Oh, Ol, Mv, Nv, Kv)

    // 1. xn = rmsnorm(hidden)
    rmsnorm_split_kernel<<<NTOK, blk, 0, stream>>>(hidden, in_ln_w, xn_hi, xn_lo, 2048, 2048);
    // 2. qa = xn @ q_a_w^T
    splitw(q_a_w, QLORA * 2048, QLORA * 2048);
    GEMM(0, xn_hi, xn_lo, qa_f32, nullptr, nullptr, nullptr, nullptr, nullptr, NTOK, QLORA, 2048);
    // 3. ckv = xn @ kv_a_w^T  (N padded 576->640 with zero rows)
    splitw(kv_a_w, CKV_LD * 2048, 576 * 2048);
    GEMM(0, xn_hi, xn_lo, ckv_f32, nullptr, nullptr, nullptr, nullptr, nullptr, NTOK, CKV_LD, 2048);
    // 4. qa_n = rmsnorm(qa)  (writes over xn slot; xn dead)
    rmsnorm_split_kernel<<<NTOK, blk, 0, stream>>>(qa_f32, q_a_ln_w, xn_hi, xn_lo, QLORA, QLORA);
    // 5. q = qa_n @ q_b_w^T
    splitw(q_b_w, 3072 * QLORA, 3072 * QLORA);
    GEMM(0, xn_hi, xn_lo, q_f32, nullptr, nullptr, nullptr, nullptr, nullptr, NTOK, 3072, QLORA);
    // 6. ckv_n = rmsnorm(ckv[:, :512]) -> w slot? no: into scratch w region is
    //    occupied next; use attn slot region (qa_f32 still live? no - dead after 5).
    rmsnorm_split_kernel<<<NTOK, blk, 0, stream>>>(ckv_f32, kv_a_ln_w, attn_hi, attn_lo, KVLORA, CKV_LD);
    // 7. kvup = ckv_n @ kv_b_w^T
    splitw(kv_b_w, 4096 * KVLORA, 4096 * KVLORA);
    GEMM(0, attn_hi, attn_lo, kvup, nullptr, nullptr, nullptr, nullptr, nullptr, NTOK, 4096, KVLORA);
    // 8. RoPE (q in place; ckv[:,512:576] -> kpe)
    rope_kernel<<<(NTOK * 17) / 8, blk, 0, stream>>>(q_f32, ckv_f32, kpe, pos_ids);
    // 9. attention -> (attn_hi, attn_lo)   (overwrites step-6 ckv_n copy: dead)
    attn_kernel<<<B_ * NH_ * 32, blk, 0, stream>>>(q_f32, kvup, kpe, attn_hi, attn_lo);
    // 10. d_out = hidden + attn @ o_w^T
    splitw(o_w, 2048 * 2048, 2048 * 2048);
    GEMM(2, attn_hi, attn_lo, out, hidden, nullptr, nullptr, nullptr, nullptr, NTOK, 2048, 2048);
    // 11. x2n = rmsnorm(d_out)  (into xn slot; qa_n dead)
    rmsnorm_split_kernel<<<NTOK, blk, 0, stream>>>(out, post_ln_w, xn_hi, xn_lo, 2048, 2048);
    // 12-14. MLP in two INTER halves; s/h aliased in [68,136); kvup dead.
    for (int half = 0; half < 2; ++half) {
        const float* gate_h = gate_w + (size_t)half * 4096 * 2048;
        const float* up_h   = up_w   + (size_t)half * 4096 * 2048;
        // s = silu(x2n @ gate_h^T)
        splitw(gate_h, 4096 * 2048, 4096 * 2048);
        GEMM(3, xn_hi, xn_lo, nullptr, nullptr, nullptr, nullptr, sh_hi, sh_lo, NTOK, 4096, 2048);
        // h = s * (x2n @ up_h^T)   (S aliases O)
        splitw(up_h, 4096 * 2048, 4096 * 2048);
        GEMM(4, xn_hi, xn_lo, nullptr, nullptr, sh_hi, sh_lo, sh_hi, sh_lo, NTOK, 4096, 2048);
        // d_out += h @ down_half^T   (down_w [2048][8192], K-slice strided)
        split_strided_kernel<<<dim3(4, 2048), blk, 0, stream>>>(
            down_w + (size_t)half * 4096, w_hi, w_lo, 4096, INTER_);
        GEMM(1, sh_hi, sh_lo, out, nullptr, nullptr, nullptr, nullptr, nullptr, NTOK, 2048, 4096);
    }
#undef GEMM
}